// Round 11
// baseline (218.117 us; speedup 1.0000x reference)
//
#include <hip/hip_runtime.h>
#include <math.h>
#include <stddef.h>

#define HQ   16
#define HKV  8
#define DH   128
#define HID  2048
#define CC   16384
#define NCH  128            // position chunks of 128 in k_softpv
#define CHUNK 128
#define NDG  8              // dim-groups of 16 in k_scores

// d_out layout (FLOAT32, 4096 elements): [attn 2048][k_new 8*128][v 8*128]
//
// ws layout (floats):
//   raw     @0        (4096)
//   qf      @4096     (2048)
//   kf      @6144     (1024)      (vnew = raw+3072)
//   ps      @8192     (2097152)   partial scores [HKV][NDG][2][CC] = 8 MB
//   opart   @2105344  (262144)    [HQ][NCH][DH]
//   ML      @2367488  (4096)      [HQ][NCH] float2
//   attn_in @2371584  (2048)

// ---- K1: QKV projections. One wave per output element.
__global__ void k_qkv(const float* __restrict__ x,
                      const float* __restrict__ Wq,
                      const float* __restrict__ Wk,
                      const float* __restrict__ Wv,
                      float* __restrict__ raw,
                      float* __restrict__ out){
  int wave = threadIdx.x >> 6, lane = threadIdx.x & 63;
  int e = blockIdx.x * 4 + wave;
  const float* W;
  if (e < 2048)      W = Wq + (size_t)e * HID;
  else if (e < 3072) W = Wk + (size_t)(e - 2048) * HID;
  else               W = Wv + (size_t)(e - 3072) * HID;
  float4 wb[8], xb[8];
  #pragma unroll
  for (int j = 0; j < 8; ++j) wb[j] = *(const float4*)(W + (j * 64 + lane) * 4);
  #pragma unroll
  for (int j = 0; j < 8; ++j) xb[j] = *(const float4*)(x + (j * 64 + lane) * 4);
  __builtin_amdgcn_sched_barrier(0);
  float acc = 0.f;
  #pragma unroll
  for (int j = 0; j < 8; ++j)
    acc += wb[j].x*xb[j].x + wb[j].y*xb[j].y + wb[j].z*xb[j].z + wb[j].w*xb[j].w;
  #pragma unroll
  for (int off = 32; off; off >>= 1) acc += __shfl_down(acc, off, 64);
  if (lane == 0){
    raw[e] = acc;
    if (e >= 3072) out[e] = acc;   // v passthrough
  }
}

// ---- K2: RMSNorm + RoPE (q,k). grid=24, 128 threads.
__global__ void k_normrope(const float* __restrict__ raw,
                           const float* __restrict__ cosb,
                           const float* __restrict__ sinb,
                           const float* __restrict__ qw,
                           const float* __restrict__ kw,
                           float* __restrict__ qf,
                           float* __restrict__ kf,
                           float* __restrict__ out){
  __shared__ float lds[DH];
  __shared__ float wsum[2];
  int b = blockIdx.x, t = threadIdx.x;
  bool isq = (b < 16);
  int h = isq ? b : b - 16;
  float val = isq ? raw[h * DH + t] : raw[2048 + h * DH + t];
  float ss = val * val;
  #pragma unroll
  for (int off = 32; off; off >>= 1) ss += __shfl_down(ss, off, 64);
  if ((t & 63) == 0) wsum[t >> 6] = ss;
  __syncthreads();
  float rms = sqrtf((wsum[0] + wsum[1]) / 128.f + 1e-6f);
  float w = isq ? qw[t] : kw[t];
  float normed = val / rms * w;
  lds[t] = normed;
  __syncthreads();
  float rot = (t < 64) ? -lds[t + 64] : lds[t - 64];
  float res = normed * cosb[t] + rot * sinb[t];
  if (isq) qf[h * DH + t] = res;
  else { kf[h * DH + t] = res; out[2048 + h * DH + t] = res; }
}

// ---- K3a: QK^T partial scores, max-concurrency streaming.
// grid = HKV*NDG*32 = 2048 blocks x 128 threads (16 waves/CU, no hot barriers).
__global__ __launch_bounds__(128) void k_scores(
    const float* __restrict__ qf,
    const float* __restrict__ kcache,  // [HKV][DH][CC]
    float* __restrict__ ps){           // [HKV][NDG][2][CC]
  __shared__ float q_s[2][16];
  int kv = blockIdx.x >> 8, dg = (blockIdx.x >> 5) & 7, cs = blockIdx.x & 31;
  int t = threadIdx.x;
  if (t < 32) q_s[t >> 4][t & 15] = qf[(kv * 2 + (t >> 4)) * DH + dg * 16 + (t & 15)];
  __syncthreads();
  const float* kp = kcache + (size_t)kv * DH * CC + (size_t)(dg * 16) * CC
                  + cs * 512 + t * 4;
  float a00 = 0.f, a01 = 0.f, a02 = 0.f, a03 = 0.f;
  float a10 = 0.f, a11 = 0.f, a12 = 0.f, a13 = 0.f;
  #pragma unroll
  for (int ib = 0; ib < 2; ++ib){
    float4 kb[8];
    #pragma unroll
    for (int j = 0; j < 8; ++j)
      kb[j] = *(const float4*)(kp + (size_t)(ib * 8 + j) * CC);
    __builtin_amdgcn_sched_barrier(0);
    #pragma unroll
    for (int j = 0; j < 8; ++j){
      float q0 = q_s[0][ib * 8 + j], q1 = q_s[1][ib * 8 + j];
      a00 += q0 * kb[j].x; a01 += q0 * kb[j].y; a02 += q0 * kb[j].z; a03 += q0 * kb[j].w;
      a10 += q1 * kb[j].x; a11 += q1 * kb[j].y; a12 += q1 * kb[j].z; a13 += q1 * kb[j].w;
    }
  }
  size_t base = ((size_t)(kv * NDG + dg) * 2) * CC + cs * 512 + t * 4;
  *(float4*)(ps + base)      = make_float4(a00, a01, a02, a03);
  *(float4*)(ps + base + CC) = make_float4(a10, a11, a12, a13);
}

// ---- K3b: combine partials, softmax per 128-chunk, PV.
// grid = HKV*NCH = 1024 blocks x 256 threads (16 waves/CU).
// Thread (h=t>>7, pos=t&127): one head-row each; per-wave softmax halves.
__global__ __launch_bounds__(256) void k_softpv(
    const float* __restrict__ ps,      // [HKV][NDG][2][CC]
    const float* __restrict__ vcache,  // [HKV][CC][DH]
    const float* __restrict__ mask,    // [CC+1]
    float* __restrict__ opart,         // [HQ][NCH][DH]
    float2* __restrict__ ml){          // [HQ][NCH]
  __shared__ float p_s[2][CHUNK];      // 1 KB
  __shared__ float part[2][8][DH];     // 8 KB
  __shared__ float red[8];
  int kv = blockIdx.x >> 7, ch = blockIdx.x & 127;
  int c0 = ch << 7;
  int t = threadIdx.x;
  const float scale = 0.08838834764831845f;  // 128^-0.5

  // gather partial dots for (head h, position pos)
  int h = t >> 7, pos = t & 127;
  float s = 0.f;
  #pragma unroll
  for (int dg = 0; dg < NDG; ++dg)
    s += ps[((size_t)(kv * NDG + dg) * 2 + h) * CC + c0 + pos];
  s = s * scale + mask[c0 + pos];

  // softmax: waves {0,1} cover h=0 pos{0-63,64-127}; waves {2,3} cover h=1.
  int wv = t >> 6;
  float lm = s;
  #pragma unroll
  for (int off = 32; off; off >>= 1) lm = fmaxf(lm, __shfl_down(lm, off, 64));
  if ((t & 63) == 0) red[wv] = lm;
  __syncthreads();
  float m = (h == 0) ? fmaxf(red[0], red[1]) : fmaxf(red[2], red[3]);
  float p = __expf(s - m);
  p_s[h][pos] = p;
  float ls = p;
  #pragma unroll
  for (int off = 32; off; off >>= 1) ls += __shfl_down(ls, off, 64);
  if ((t & 63) == 0) red[4 + wv] = ls;
  __syncthreads();
  if (pos == 0){
    float l = red[4 + h * 2] + red[5 + h * 2];
    ml[(size_t)(kv * 2 + h) * NCH + ch] = make_float2(m, l);
  }

  // PV: 8 pos-slices x 32 dim-lanes; pinned 8-deep batches; V contiguous.
  {
    int sl = t >> 5, d4 = (t & 31) * 4;
    const float* vbase = vcache + (size_t)kv * CC * DH + (size_t)c0 * DH + d4;
    float4 a0 = make_float4(0.f, 0.f, 0.f, 0.f);
    float4 a1 = make_float4(0.f, 0.f, 0.f, 0.f);
    #pragma unroll
    for (int ib = 0; ib < 2; ++ib){
      float4 vv[8];
      #pragma unroll
      for (int j = 0; j < 8; ++j){
        int off = (ib * 8 + j) * 8 + sl;
        vv[j] = *(const float4*)(vbase + (size_t)off * DH);
      }
      __builtin_amdgcn_sched_barrier(0);
      #pragma unroll
      for (int j = 0; j < 8; ++j){
        int off = (ib * 8 + j) * 8 + sl;
        float pp0 = p_s[0][off], pp1 = p_s[1][off];
        a0.x += pp0 * vv[j].x; a0.y += pp0 * vv[j].y; a0.z += pp0 * vv[j].z; a0.w += pp0 * vv[j].w;
        a1.x += pp1 * vv[j].x; a1.y += pp1 * vv[j].y; a1.z += pp1 * vv[j].z; a1.w += pp1 * vv[j].w;
      }
    }
    *(float4*)&part[0][sl][d4] = a0;
    *(float4*)&part[1][sl][d4] = a1;
  }
  __syncthreads();
  {
    int hh = t >> 7, d = t & 127;
    float o = 0.f;
    #pragma unroll
    for (int ss = 0; ss < 8; ++ss) o += part[hh][ss][d];
    int qh = kv * 2 + hh;
    opart[((size_t)qh * NCH + ch) * DH + d] = o;
  }
}

// ---- K4: combine chunk partials + new-token term. grid=HQ, 512 threads.
// NCH=128: each wave covers all 128 chunk-maxes via two loads; 4 groups x 32.
__global__ void k_combine(const float* __restrict__ opart,
                          const float2* __restrict__ ml,
                          const float* __restrict__ qf,
                          const float* __restrict__ kf,
                          const float* __restrict__ vnew,   // raw+3072: [HKV][DH]
                          const float* __restrict__ mask,
                          float* __restrict__ attn_in){
  __shared__ float osum[4][DH];
  __shared__ float Ls[4];
  __shared__ float redq[2];
  int qh = blockIdx.x, t = threadIdx.x;
  int g = t >> 7, d = t & 127;
  int kv = qh >> 1;
  const float2* mlrow = ml + (size_t)qh * NCH;
  // each wave independently computes the global max over 128 chunks
  float mm = fmaxf(mlrow[t & 63].x, mlrow[64 + (t & 63)].x);
  #pragma unroll
  for (int off = 32; off; off >>= 1) mm = fmaxf(mm, __shfl_down(mm, off, 64));
  float M = __shfl(mm, 0, 64);
  // per-group merge of 32 chunks
  float o = 0.f, L = 0.f;
  int ch0 = g * 32;
  #pragma unroll 4
  for (int i = 0; i < 32; ++i){
    float2 m2 = mlrow[ch0 + i];
    float w = __expf(m2.x - M);
    L += m2.y * w;
    o += w * opart[((size_t)qh * NCH + ch0 + i) * DH + d];
  }
  osum[g][d] = o;
  if (d == 0) Ls[g] = L;
  if (t < DH){
    float sum = qf[qh * DH + t] * kf[kv * DH + t];
    #pragma unroll
    for (int off = 32; off; off >>= 1) sum += __shfl_down(sum, off, 64);
    if ((t & 63) == 0) redq[t >> 6] = sum;
  }
  __syncthreads();
  if (t < DH){
    float s_new = (redq[0] + redq[1]) * 0.08838834764831845f + mask[CC];
    float pn = __expf(s_new - M);
    float Lf = Ls[0] + Ls[1] + Ls[2] + Ls[3] + pn;
    float of = osum[0][t] + osum[1][t] + osum[2][t] + osum[3][t]
             + pn * vnew[kv * DH + t];
    attn_in[qh * DH + t] = of / Lf;
  }
}

// ---- K5: o_proj GEMV. One wave per output element, pinned 8-deep batch.
__global__ void k_oproj(const float* __restrict__ attn_in,
                        const float* __restrict__ Wo,
                        float* __restrict__ out){
  int wave = threadIdx.x >> 6, lane = threadIdx.x & 63;
  int e = blockIdx.x * 4 + wave;
  const float* W = Wo + (size_t)e * HID;
  float4 wb[8], xb[8];
  #pragma unroll
  for (int j = 0; j < 8; ++j) wb[j] = *(const float4*)(W + (j * 64 + lane) * 4);
  #pragma unroll
  for (int j = 0; j < 8; ++j) xb[j] = *(const float4*)(attn_in + (j * 64 + lane) * 4);
  __builtin_amdgcn_sched_barrier(0);
  float acc = 0.f;
  #pragma unroll
  for (int j = 0; j < 8; ++j)
    acc += wb[j].x*xb[j].x + wb[j].y*xb[j].y + wb[j].z*xb[j].z + wb[j].w*xb[j].w;
  #pragma unroll
  for (int off = 32; off; off >>= 1) acc += __shfl_down(acc, off, 64);
  if (lane == 0) out[e] = acc;
}

extern "C" void kernel_launch(void* const* d_in, const int* in_sizes, int n_in,
                              void* d_out, int out_size, void* d_ws, size_t ws_size,
                              hipStream_t stream){
  const float* x    = (const float*)d_in[0];
  const float* cosb = (const float*)d_in[1];
  const float* sinb = (const float*)d_in[2];
  const float* mask = (const float*)d_in[3];
  const float* kc   = (const float*)d_in[4];
  const float* vc   = (const float*)d_in[5];
  const float* Wq   = (const float*)d_in[6];
  const float* Wk   = (const float*)d_in[7];
  const float* Wv   = (const float*)d_in[8];
  const float* Wo   = (const float*)d_in[9];
  const float* qw   = (const float*)d_in[10];
  const float* kw   = (const float*)d_in[11];
  float* out = (float*)d_out;
  float* ws = (float*)d_ws;
  float* raw     = ws;                          // 4096
  float* qf      = ws + 4096;                   // 2048
  float* kf      = ws + 6144;                   // 1024
  float* ps      = ws + 8192;                   // 8*8*2*16384 = 2097152
  float* opart   = ws + 2105344;                // 16*128*128 = 262144
  float2* ML     = (float2*)(ws + 2367488);     // 2048 float2 = 4096 floats
  float* attn_in = ws + 2371584;                // 2048

  k_qkv     <<<1024, 256, 0, stream>>>(x, Wq, Wk, Wv, raw, out);
  k_normrope<<<24,   128, 0, stream>>>(raw, cosb, sinb, qw, kw, qf, kf, out);
  k_scores  <<<HKV * NDG * 32, 128, 0, stream>>>(qf, kc, ps);
  k_softpv  <<<HKV * NCH, 256, 0, stream>>>(ps, vc, mask, opart, ML);
  k_combine <<<HQ, 512, 0, stream>>>(opart, ML, qf, kf, raw + 3072, mask, attn_in);
  k_oproj   <<<512, 256, 0, stream>>>(attn_in, Wo, out);
}